// Round 8
// baseline (1292.559 us; speedup 1.0000x reference)
//
#include <hip/hip_runtime.h>

// LightGCN propagation: ego = concat(user,item); 3x { ego = A@ego; acc += ego }
// Round-10 = round-9 (1292us: bucket build -> row-sorted CSR -> acc-free spmm,
// fused final reduction) + COLUMN-CHUNK SECONDARY SORT:
//  - k_bsort key: rl -> (rl, col>>15): 147x16 = 2352 bins. CSR row order kept
//    (row_ptr = chunk-0 bin offsets); within each row, edges ordered by col
//    chunk. All ~32K concurrent spmm waves sweep columns in lockstep -> active
//    gather window ~1-2 chunks (4-8MB of ego) instead of the full 38.4MB ->
//    ego gathers become L2/L3-resident. Theory target: spmm FETCH 858MB ->
//    ~300-450MB (ego compulsory 38.4MB + streams), dur 266 -> ~200us/layer.
//  - k_spmm byte-identical to the proven round-9 kernel; only data order changes.
//  - bsort scan now block-parallel (2352 bins); LDS 61.5KB -> 2 wg/CU.

typedef unsigned short u16;
typedef unsigned int   u32;
typedef unsigned long long u64;

#define USER_ELEMS   (200000 * 64)
#define N_NODES      300000
#define EMB          64
#define NNZ          12800000
#define TOTAL_ELEMS  (N_NODES * EMB)     // 19,200,000

// ---- T0 bucket geometry ----
#define NBUCK    2048
#define ROWS_PB  147                     // 2048*147 = 301,056 >= 300,000
#define EPB      65536                   // edges per block in A passes
#define NB_A     196                     // ceil(NNZ / EPB)
#define CNT_LEN  (NBUCK * NB_A)          // 401,408
#define TILE     4096
#define NTILES   (EPB / TILE)            // 16
#define BCAP     6784                    // bucket LDS capacity (mean 6272, +6.5 sigma)
#define NCH      16                      // col chunks: (col&0x7FFFF)>>15 in [0,15]
#define KEYS     (ROWS_PB * NCH)         // 2352
#define KPT      ((KEYS + 511) / 512)    // 5 bins/thread in bsort scan

// workspace region sizes (bytes)
#define FLAGS_SZ   256ULL
#define ACC_SZ     76800000ULL           // fp32 acc (T2/T3 fallbacks only)
#define EGO_SZ     38400000ULL           // bf16 ego
#define RP_SZ      1200128ULL            // row_ptr (300,032 ints)
#define BS_SZ      1024ULL
#define CNTM_SZ    1605632ULL            // CNT_LEN * 4
#define COL_SZ     51200000ULL           // u32 col per edge (CSR)
#define VALSORT_SZ 25600000ULL           // bf16 val per edge (CSR)
#define BIG_SZ     115200000ULL          // max(stage u64 102.4M, e0+e1+e2 115.2M)
#define PERM_SZ    51200000ULL
#define LAYER_SZ   76800000ULL

#define T0_NEED (FLAGS_SZ + CNTM_SZ + 2*BS_SZ + COL_SZ + VALSORT_SZ + RP_SZ + BIG_SZ) // 194,808,064
#define T2_NEED (FLAGS_SZ + ACC_SZ + EGO_SZ + 2*RP_SZ + 2*BS_SZ + PERM_SZ)            // 168,802,560

__device__ __forceinline__ float bf2f(u16 b) {
    return __uint_as_float(((u32)b) << 16);
}
__device__ __forceinline__ u16 f2bf(float f) {
    u32 u = __float_as_uint(f);
    u32 r = (u + 0x7fffu + ((u >> 16) & 1u)) >> 16;   // round-to-nearest-even
    return (u16)r;
}

// ---------------- dtype detection ----------------
__global__ void k_detect(const u16* __restrict__ emb, const u16* __restrict__ vals,
                         int* __restrict__ flags) {
    int lane = threadIdx.x;                 // 64 threads, 1 wave
    u16 a = emb[lane * 2];
    int ea = (a >> 7) & 0xFF;
    bool pa = (ea >= 0x60 && ea <= 0x7E);
    unsigned long long ba = __ballot(pa);
    u16 b = vals[lane * 2];
    int eb = (b >> 7) & 0xFF;
    bool pb = (eb >= 0x60 && eb <= 0x7E);
    unsigned long long bb = __ballot(pb);
    if (lane == 0) {
        flags[0] = (__popcll(ba) >= 56) ? 0 : 1;   // 0 = bf16, 1 = fp32
        flags[1] = (__popcll(bb) >= 56) ? 0 : 1;
    }
}

// ---------------- init (T0): ego0 bf16 only ----------------
__global__ void k_init_ego(const void* __restrict__ user, const void* __restrict__ item,
                           const int* __restrict__ flags, u16* __restrict__ ego) {
    int t = blockIdx.x * blockDim.x + threadIdx.x;
    int e = t * 4;
    if (e >= TOTAL_ELEMS) return;
    float4 f;
    if (flags[0]) {
        const float* src = (e < USER_ELEMS) ? ((const float*)user + e)
                                            : ((const float*)item + (e - USER_ELEMS));
        f = *(const float4*)src;
    } else {
        const u16* src = (e < USER_ELEMS) ? ((const u16*)user + e)
                                          : ((const u16*)item + (e - USER_ELEMS));
        ushort4 v = *(const ushort4*)src;
        f.x = bf2f(v.x); f.y = bf2f(v.y); f.z = bf2f(v.z); f.w = bf2f(v.w);
    }
    ushort4 o;
    o.x = f2bf(f.x); o.y = f2bf(f.y); o.z = f2bf(f.z); o.w = f2bf(f.w);
    *(ushort4*)(ego + e) = o;
}

// ---------------- init (T2/T3): ego0 bf16 + acc fp32 ----------------
__global__ void k_init(const void* __restrict__ user, const void* __restrict__ item,
                       const int* __restrict__ flags,
                       u16* __restrict__ ego, float* __restrict__ acc) {
    int t = blockIdx.x * blockDim.x + threadIdx.x;
    int e = t * 4;
    if (e >= TOTAL_ELEMS) return;
    float4 f;
    if (flags[0]) {
        const float* src = (e < USER_ELEMS) ? ((const float*)user + e)
                                            : ((const float*)item + (e - USER_ELEMS));
        f = *(const float4*)src;
    } else {
        const u16* src = (e < USER_ELEMS) ? ((const u16*)user + e)
                                          : ((const u16*)item + (e - USER_ELEMS));
        ushort4 v = *(const ushort4*)src;
        f.x = bf2f(v.x); f.y = bf2f(v.y); f.z = bf2f(v.z); f.w = bf2f(v.w);
    }
    ushort4 o;
    o.x = f2bf(f.x); o.y = f2bf(f.y); o.z = f2bf(f.z); o.w = f2bf(f.w);
    *(ushort4*)(ego + e) = o;
    *(float4*)(acc + e) = f;
}

// ---------------- generic 3-phase exclusive scan (EPT = elems/thread) ----------------
template<int EPT>
__global__ void k_scan_reduce(const int* __restrict__ cnt, int* __restrict__ blockSums,
                              int n) {
    __shared__ int s[256];
    int b = blockIdx.x;
    int base = b * (EPT * 256) + threadIdx.x;
    int sum = 0;
#pragma unroll
    for (int k = 0; k < EPT; ++k) {
        int i = base + k * 256;
        if (i < n) sum += cnt[i];
    }
    s[threadIdx.x] = sum;
    __syncthreads();
    for (int off = 128; off > 0; off >>= 1) {
        if (threadIdx.x < (unsigned)off) s[threadIdx.x] += s[threadIdx.x + off];
        __syncthreads();
    }
    if (threadIdx.x == 0) blockSums[b] = s[0];
}

__global__ void k_scan_block(const int* __restrict__ blockSums, int* __restrict__ blockOffs,
                             int nb) {
    __shared__ int s[256];
    int x = (threadIdx.x < nb) ? blockSums[threadIdx.x] : 0;
    s[threadIdx.x] = x;
    __syncthreads();
    for (int off = 1; off < 256; off <<= 1) {
        int t = 0;
        if (threadIdx.x >= (unsigned)off) t = s[threadIdx.x - off];
        __syncthreads();
        s[threadIdx.x] += t;
        __syncthreads();
    }
    if (threadIdx.x < nb) blockOffs[threadIdx.x] = s[threadIdx.x] - x;
}

// In-place safe. cursor2 may be null; may alias cnt.
template<int EPT>
__global__ void k_scan_down(const int* cnt, const int* __restrict__ blockOffs,
                            int* __restrict__ out, int* cursor2,
                            int n, int total, int writeTotal) {
    __shared__ int s[256];
    int b = blockIdx.x;
    int base = b * (EPT * 256) + threadIdx.x * EPT;
    int v[EPT];
    int tsum = 0;
#pragma unroll
    for (int k = 0; k < EPT; ++k) {
        int i = base + k;
        v[k] = (i < n) ? cnt[i] : 0;
        tsum += v[k];
    }
    s[threadIdx.x] = tsum;
    __syncthreads();
    for (int off = 1; off < 256; off <<= 1) {
        int t = 0;
        if (threadIdx.x >= (unsigned)off) t = s[threadIdx.x - off];
        __syncthreads();
        s[threadIdx.x] += t;
        __syncthreads();
    }
    int running = blockOffs[b] + (s[threadIdx.x] - tsum);
#pragma unroll
    for (int k = 0; k < EPT; ++k) {
        int i = base + k;
        if (i < n) {
            out[i] = running;
            if (cursor2) cursor2[i] = running;
        }
        running += v[k];
    }
    if (writeTotal && b == 0 && threadIdx.x == 0) out[n] = total;
}

// ---------------- A1: per-block bucket histogram ----------------
__global__ void __launch_bounds__(512) k_bhist(const int* __restrict__ rows,
                                               int* __restrict__ counts) {
    __shared__ int c[NBUCK];
    for (int i = threadIdx.x; i < NBUCK; i += 512) c[i] = 0;
    __syncthreads();
    int b0 = blockIdx.x * EPB;
    for (int i = threadIdx.x; i < EPB; i += 512) {
        int e = b0 + i;
        if (e < NNZ) {
            u32 k = (u32)rows[e] / ROWS_PB;
            if (k >= NBUCK) k = NBUCK - 1;          // guard: bad row -> clamp
            atomicAdd(&c[k], 1);
        }
    }
    __syncthreads();
    for (int k = threadIdx.x; k < NBUCK; k += 512)
        counts[k * NB_A + blockIdx.x] = c[k];
}

// ---------------- A3: tile-staged multisplit scatter ----------------
__global__ void __launch_bounds__(512) k_bscatter(
    const int* __restrict__ rows, const int* __restrict__ cols,
    const void* __restrict__ vals, const int* __restrict__ flags,
    const int* __restrict__ offs, u64* __restrict__ stg) {
    __shared__ int h[NBUCK];        // 8KB  per-tile bucket counts
    __shared__ u16 o[NBUCK];        // 4KB  inclusive scan of h (<=4096 fits u16)
    __shared__ int gbase[NBUCK];    // 8KB  running global write base per bucket
    __shared__ u64 st[TILE];        // 32KB staged payloads
    __shared__ u16 kst[TILE];       // 8KB  staged bucket ids      (total 60KB)
    int b = blockIdx.x, tid = threadIdx.x;
    for (int i = tid; i < NBUCK; i += 512) gbase[i] = offs[i * NB_A + b];
    int valF32 = flags[1];
    for (int t = 0; t < NTILES; ++t) {
        for (int i = tid; i < NBUCK; i += 512) h[i] = 0;
        __syncthreads();
        int ebase = b * EPB + t * TILE;
        int kk[8]; int rk[8]; u64 pl[8];
#pragma unroll
        for (int j = 0; j < 8; ++j) {
            int e = ebase + tid + j * 512;
            kk[j] = -1;
            if (e < NNZ) {
                u32 r = (u32)rows[e];
                u32 c = (u32)cols[e] & 0x7FFFFu;     // guard: 19-bit col
                u16 v = valF32 ? f2bf(((const float*)vals)[e]) : ((const u16*)vals)[e];
                u32 k = r / ROWS_PB;
                if (k >= NBUCK) k = NBUCK - 1;       // guard: bad row -> clamp
                u32 rl = r - k * ROWS_PB;
                if (rl >= ROWS_PB) rl = ROWS_PB - 1; // guard
                kk[j] = (int)k;
                pl[j] = ((u64)v << 32) | (u64)((rl << 19) | c);
                rk[j] = atomicAdd(&h[k], 1);
            }
        }
        __syncthreads();
        for (int i = tid; i < NBUCK; i += 512) o[i] = (u16)h[i];
        __syncthreads();
        for (int off = 1; off < NBUCK; off <<= 1) {   // Hillis-Steele inclusive
            u16 t0[4];
#pragma unroll
            for (int q = 0; q < 4; ++q) {
                int i = tid + q * 512;
                t0[q] = (i >= off) ? o[i - off] : (u16)0;
            }
            __syncthreads();
#pragma unroll
            for (int q = 0; q < 4; ++q) o[tid + q * 512] += t0[q];
            __syncthreads();
        }
#pragma unroll
        for (int j = 0; j < 8; ++j) {
            if (kk[j] >= 0) {
                int excl = (int)o[kk[j]] - h[kk[j]];
                int p = excl + rk[j];
                if (p >= 0 && p < TILE) {            // guard: never OOB LDS
                    st[p] = pl[j];
                    kst[p] = (u16)kk[j];
                }
            }
        }
        __syncthreads();
        int cnt = (int)o[NBUCK - 1];
        if (cnt > TILE) cnt = TILE;                  // guard
        for (int i = tid; i < cnt; i += 512) {
            int k = kst[i];
            int excl = (int)o[k] - h[k];
            long long p = (long long)gbase[k] + (i - excl);
            if (p >= 0 && p < NNZ) stg[p] = st[i];   // guard: never OOB global
        }
        __syncthreads();
        for (int i = tid; i < NBUCK; i += 512) gbase[i] += h[i];
        __syncthreads();
    }
}

// ---------------- B: per-bucket (row, col-chunk) sort -> CSR + row_ptr ----------------
// Key = rl*16 + (col>>15): row-major CSR preserved; within-row edges ordered by
// column chunk so concurrent spmm waves sweep a compact ego window together.
__global__ void __launch_bounds__(512) k_bsort(
    const int* __restrict__ offs, const u64* __restrict__ stg,
    int* __restrict__ col_s, u16* __restrict__ val_s, int* __restrict__ row_ptr) {
    __shared__ int h[KEYS];             // 9,408B  bin counts
    __shared__ int ex[KEYS];            // 9,408B  exclusive offsets -> cursors
    __shared__ int s512[512];           // 2,048B  block scan
    __shared__ u32 lcol[BCAP];          // 27,136B
    __shared__ u16 lval[BCAP];          // 13,568B  (total 61.5KB -> 2 wg/CU)
    int k = blockIdx.x, tid = threadIdx.x;
    int s = offs[k * NB_A];
    int e = (k == NBUCK - 1) ? NNZ : offs[(k + 1) * NB_A];
    if (e > NNZ) e = NNZ;                            // guard
    if (s < 0) s = 0;                                // guard
    for (int i = tid; i < KEYS; i += 512) h[i] = 0;
    __syncthreads();
    for (int j = s + tid; j < e; j += 512) {
        u32 lo = (u32)stg[j];
        u32 rl = lo >> 19;
        if (rl >= ROWS_PB) rl = ROWS_PB - 1;         // guard (stale staging)
        u32 ch = (lo & 0x7FFFFu) >> 15;              // 0..15 by construction
        atomicAdd(&h[rl * NCH + ch], 1);
    }
    __syncthreads();
    // block-parallel exclusive scan over KEYS bins (KPT bins/thread)
    int loc[KPT]; int tsum = 0; int base = tid * KPT;
#pragma unroll
    for (int q = 0; q < KPT; ++q) {
        int i = base + q;
        loc[q] = (i < KEYS) ? h[i] : 0;
        tsum += loc[q];
    }
    s512[tid] = tsum;
    __syncthreads();
    for (int off = 1; off < 512; off <<= 1) {
        int t = 0;
        if (tid >= off) t = s512[tid - off];
        __syncthreads();
        s512[tid] += t;
        __syncthreads();
    }
    int run = s512[tid] - tsum;
#pragma unroll
    for (int q = 0; q < KPT; ++q) {
        int i = base + q;
        if (i < KEYS) { ex[i] = run; run += loc[q]; }
    }
    __syncthreads();
    // row_ptr from chunk-0 bins (before ex is consumed as cursors)
    int rowbase = k * ROWS_PB;
    for (int i = tid; i < ROWS_PB; i += 512) {
        int r = rowbase + i;
        if (r <= N_NODES) row_ptr[r] = s + ex[i * NCH];
    }
    __syncthreads();
    int n = e - s;
    for (int j = s + tid; j < e; j += 512) {
        u64 pk = stg[j];
        u32 lo = (u32)pk;
        u32 rl = lo >> 19;
        if (rl >= ROWS_PB) rl = ROWS_PB - 1;         // guard
        u32 ch = (lo & 0x7FFFFu) >> 15;
        int p = atomicAdd(&ex[rl * NCH + ch], 1);
        if (p >= 0 && p < BCAP) { lcol[p] = lo & 0x7FFFFu; lval[p] = (u16)(pk >> 32); }
        else if (p >= 0 && p < n) {                  // overflow fallback, guarded
            col_s[s + p] = (int)(lo & 0x7FFFFu); val_s[s + p] = (u16)(pk >> 32);
        }
    }
    __syncthreads();
    int m = n < BCAP ? n : BCAP;
    for (int i = tid; i < m; i += 512) {
        col_s[s + i] = (int)lcol[i];
        val_s[s + i] = lval[i];
    }
}

// ---------------- SpMM: wave per row, lane = emb dim ----------------
// FINAL=0: writes ego_out bf16. FINAL=1 (layer 3): fuses the output reduction
// out = (e0 + e1 + e2 + a3) / 4 and writes d_out (fp32 or bf16) directly.
template<int FINAL>
__global__ void __launch_bounds__(256) k_spmm(
    const int* __restrict__ row_ptr, const int* __restrict__ col_s,
    const u16* __restrict__ val_s, const u16* __restrict__ ego_in,
    u16* __restrict__ ego_out,
    const u16* __restrict__ e0, const u16* __restrict__ e1,
    const int* __restrict__ flags, void* __restrict__ out) {
    int row = __builtin_amdgcn_readfirstlane(
        (int)((blockIdx.x * blockDim.x + threadIdx.x) >> 6));
    int lane = threadIdx.x & 63;
    if (row >= N_NODES) return;
    int start = row_ptr[row];
    int end   = row_ptr[row + 1];
    float a = 0.f;
    int j = start;
    for (; j + 8 <= end; j += 8) {
        int c[8]; u16 w[8];
#pragma unroll
        for (int q = 0; q < 8; ++q) { c[q] = col_s[j + q]; w[q] = val_s[j + q]; }
        float x[8];
#pragma unroll
        for (int q = 0; q < 8; ++q) {
            u32 cc = (u32)c[q] & 0x7FFFFu;           // bounded gather
            x[q] = bf2f(ego_in[cc * EMB + lane]);
        }
#pragma unroll
        for (int q = 0; q < 8; ++q) a += bf2f(w[q]) * x[q];
    }
    for (; j < end; ++j) {
        u32 cc = (u32)col_s[j] & 0x7FFFFu;
        a += bf2f(val_s[j]) * bf2f(ego_in[cc * EMB + lane]);
    }
    int o = row * EMB + lane;
    if (FINAL) {
        float s = bf2f(e0[o]) + bf2f(e1[o]) + bf2f(ego_in[o]) + a;  // ego_in == e2
        s *= 0.25f;
        if (flags[0]) ((float*)out)[o] = s;
        else          ((u16*)out)[o]  = f2bf(s);
    } else {
        ego_out[o] = f2bf(a);
    }
}

// ---------------- T2 fallback: CSR by permutation ----------------
__global__ void k_hist(const int* __restrict__ rows, int* __restrict__ cnt) {
    int e = blockIdx.x * blockDim.x + threadIdx.x;
    if (e < NNZ) atomicAdd(&cnt[rows[e]], 1);
}

__global__ void k_scatter_perm(const int* __restrict__ rows, int* __restrict__ cursor,
                               u32* __restrict__ perm) {
    int e = blockIdx.x * blockDim.x + threadIdx.x;
    if (e >= NNZ) return;
    int r = rows[e];
    int p = atomicAdd(&cursor[r], 1);
    perm[p] = (u32)e;
}

__global__ void __launch_bounds__(256) k_spmm_perm(
    const int* __restrict__ row_ptr, const u32* __restrict__ perm,
    const int* __restrict__ cols, const void* __restrict__ vals,
    const int* __restrict__ flags, const u16* __restrict__ ego_in,
    u16* __restrict__ ego_out, float* __restrict__ acc) {
    int row = __builtin_amdgcn_readfirstlane(
        (int)((blockIdx.x * blockDim.x + threadIdx.x) >> 6));
    int lane = threadIdx.x & 63;
    if (row >= N_NODES) return;
    int valF32 = flags[1];
    int start = row_ptr[row];
    int end   = row_ptr[row + 1];
    float a = 0.f;
    for (int j = start; j < end; ++j) {
        u32 eid = perm[j];
        int c = cols[eid];
        float w = valF32 ? ((const float*)vals)[eid] : bf2f(((const u16*)vals)[eid]);
        a += w * bf2f(ego_in[c * EMB + lane]);
    }
    int o = row * EMB + lane;
    acc[o] += a;
    ego_out[o] = f2bf(a);
}

// ---------------- T3 fallback: edge-parallel atomics ----------------
__global__ void __launch_bounds__(256) k_edge_atomic(
    const int* __restrict__ rows, const int* __restrict__ cols,
    const void* __restrict__ vals, const int* __restrict__ flags,
    const u16* __restrict__ ego, float* __restrict__ layer) {
    int t = blockIdx.x * blockDim.x + threadIdx.x;
    int e = t >> 4;
    if (e >= NNZ) return;
    int d4 = (t & 15) * 4;
    int r = rows[e], c = cols[e];
    float w = flags[1] ? ((const float*)vals)[e] : bf2f(((const u16*)vals)[e]);
    ushort4 x = *(const ushort4*)(ego + c * EMB + d4);
    float* dst = layer + r * EMB + d4;
    atomicAdd(dst + 0, w * bf2f(x.x));
    atomicAdd(dst + 1, w * bf2f(x.y));
    atomicAdd(dst + 2, w * bf2f(x.z));
    atomicAdd(dst + 3, w * bf2f(x.w));
}

__global__ void k_layer_fin(float* __restrict__ layer, float* __restrict__ acc,
                            u16* __restrict__ ego) {
    int t = blockIdx.x * blockDim.x + threadIdx.x;
    int e = t * 4;
    if (e >= TOTAL_ELEMS) return;
    float4 L = *(const float4*)(layer + e);
    float4 A = *(const float4*)(acc + e);
    A.x += L.x; A.y += L.y; A.z += L.z; A.w += L.w;
    *(float4*)(acc + e) = A;
    ushort4 o;
    o.x = f2bf(L.x); o.y = f2bf(L.y); o.z = f2bf(L.z); o.w = f2bf(L.w);
    *(ushort4*)(ego + e) = o;
    float4 z; z.x = 0.f; z.y = 0.f; z.z = 0.f; z.w = 0.f;
    *(float4*)(layer + e) = z;
}

// ---------------- finalize (T2/T3): out = (acc / 4) ----------------
__global__ void k_final(const float* __restrict__ acc, const int* __restrict__ flags,
                        void* __restrict__ out) {
    int t = blockIdx.x * blockDim.x + threadIdx.x;
    int e = t * 4;
    if (e >= TOTAL_ELEMS) return;
    float4 f = *(const float4*)(acc + e);
    f.x *= 0.25f; f.y *= 0.25f; f.z *= 0.25f; f.w *= 0.25f;
    if (flags[0]) {
        *(float4*)((float*)out + e) = f;
    } else {
        ushort4 v;
        v.x = f2bf(f.x); v.y = f2bf(f.y); v.z = f2bf(f.z); v.w = f2bf(f.w);
        *(ushort4*)((u16*)out + e) = v;
    }
}

extern "C" void kernel_launch(void* const* d_in, const int* in_sizes, int n_in,
                              void* d_out, int out_size, void* d_ws, size_t ws_size,
                              hipStream_t stream) {
    const void* user = d_in[0];
    const void* item = d_in[1];
    const void* vals = d_in[2];
    const int*  rows = (const int*)d_in[3];
    const int*  cols = (const int*)d_in[4];

    char* ws = (char*)d_ws;
    int* flags = (int*)ws;

    const int initGrid = (TOTAL_ELEMS / 4 + 255) / 256;   // 18750
    const int edgeGrid = (NNZ + 255) / 256;                // 50000
    const int spmmGrid = (N_NODES * 64) / 256;             // 75000

    k_detect<<<1, 64, 0, stream>>>((const u16*)user, (const u16*)vals, flags);

    if (ws_size >= T0_NEED) {
        // ---- T0: bucket build -> CSR (col-chunk ordered) -> 3x spmm ----
        size_t off = FLAGS_SZ;
        int* cntm = (int*)(ws + off); off += CNTM_SZ;     // counts -> offsets (in place)
        int* bs2  = (int*)(ws + off); off += BS_SZ;
        int* bo2  = (int*)(ws + off); off += BS_SZ;
        int* col_s = (int*)(ws + off); off += COL_SZ;     // plain col (CSR order)
        u16* val_s = (u16*)(ws + off); off += VALSORT_SZ;
        int* row_ptr = (int*)(ws + off); off += RP_SZ;
        char* big  = ws + off;                            // 115.2MB shared region
        u64* stg = (u64*)big;                             // staging (dead after k_bsort)
        u16* e0  = (u16*)big;                             // live after k_init_ego
        u16* e1  = (u16*)(big + EGO_SZ);
        u16* e2  = (u16*)(big + 2 * EGO_SZ);

        k_bhist<<<NB_A, 512, 0, stream>>>(rows, cntm);
        // k-major exclusive scan of the 2048 x 196 count matrix (in place)
        k_scan_reduce<16><<<98, 256, 0, stream>>>(cntm, bs2, CNT_LEN);
        k_scan_block<<<1, 256, 0, stream>>>(bs2, bo2, 98);
        k_scan_down<16><<<98, 256, 0, stream>>>(cntm, bo2, cntm, (int*)0, CNT_LEN, 0, 0);

        k_bscatter<<<NB_A, 512, 0, stream>>>(rows, cols, vals, flags, cntm, stg);
        k_bsort<<<NBUCK, 512, 0, stream>>>(cntm, stg, col_s, val_s, row_ptr);

        k_init_ego<<<initGrid, 256, 0, stream>>>(user, item, flags, e0); // after bsort: e0 aliases stg
        // dummy (valid) pointers for unused template-dead args
        k_spmm<0><<<spmmGrid, 256, 0, stream>>>(row_ptr, col_s, val_s, e0, e1,
                                                e0, e1, flags, (void*)d_out);
        k_spmm<0><<<spmmGrid, 256, 0, stream>>>(row_ptr, col_s, val_s, e1, e2,
                                                e0, e1, flags, (void*)d_out);
        k_spmm<1><<<spmmGrid, 256, 0, stream>>>(row_ptr, col_s, val_s, e2, e1,
                                                e0, e1, flags, d_out);
    } else if (ws_size >= T2_NEED) {
        // ---- T2: permutation CSR ----
        size_t off = FLAGS_SZ;
        float* acc = (float*)(ws + off); off += ACC_SZ;
        u16* ego0 = (u16*)d_out;
        u16* ego1 = (u16*)(ws + off); off += EGO_SZ;
        int* row_ptr = (int*)(ws + off); off += RP_SZ;
        int* cursor  = (int*)(ws + off); off += RP_SZ;
        int* bsums   = (int*)(ws + off); off += BS_SZ;
        int* boffs   = (int*)(ws + off); off += BS_SZ;
        u32* perm    = (u32*)(ws + off); off += PERM_SZ;

        hipMemsetAsync(cursor, 0, N_NODES * sizeof(int), stream);
        k_init<<<initGrid, 256, 0, stream>>>(user, item, flags, ego0, acc);
        k_hist<<<edgeGrid, 256, 0, stream>>>(rows, cursor);
        k_scan_reduce<8><<<147, 256, 0, stream>>>(cursor, bsums, N_NODES);
        k_scan_block<<<1, 256, 0, stream>>>(bsums, boffs, 147);
        k_scan_down<8><<<147, 256, 0, stream>>>(cursor, boffs, row_ptr, cursor,
                                                N_NODES, NNZ, 1);
        k_scatter_perm<<<edgeGrid, 256, 0, stream>>>(rows, cursor, perm);
        k_spmm_perm<<<spmmGrid, 256, 0, stream>>>(row_ptr, perm, cols, vals, flags,
                                                  ego0, ego1, acc);
        k_spmm_perm<<<spmmGrid, 256, 0, stream>>>(row_ptr, perm, cols, vals, flags,
                                                  ego1, ego0, acc);
        k_spmm_perm<<<spmmGrid, 256, 0, stream>>>(row_ptr, perm, cols, vals, flags,
                                                  ego0, ego1, acc);
        k_final<<<initGrid, 256, 0, stream>>>(acc, flags, d_out);
    } else {
        // ---- T3: edge-parallel atomics, minimal footprint ----
        size_t off = FLAGS_SZ;
        float* acc   = (float*)(ws + off); off += ACC_SZ;
        float* layer = (float*)(ws + off); off += LAYER_SZ;
        u16* ego = (u16*)d_out;
        hipMemsetAsync(layer, 0, LAYER_SZ, stream);
        k_init<<<initGrid, 256, 0, stream>>>(user, item, flags, ego, acc);
        const int atomGrid = (NNZ * 16) / 256;
        for (int l = 0; l < 3; ++l) {
            k_edge_atomic<<<atomGrid, 256, 0, stream>>>(rows, cols, vals, flags, ego, layer);
            k_layer_fin<<<initGrid, 256, 0, stream>>>(layer, acc, ego);
        }
        k_final<<<initGrid, 256, 0, stream>>>(acc, flags, d_out);
    }
}

// Round 9
// 1252.131 us; speedup vs baseline: 1.0323x; 1.0323x over previous
//
#include <hip/hip_runtime.h>

// LightGCN propagation: ego = concat(user,item); 3x { ego = A@ego; acc += ego }
// Round-11 = round-9/10 (1292us) with ONE change: k_spmm gather unroll 8 -> 16
// (+4-wide mid loop). Theory: spmm is outstanding-miss limited (12.8 cyc/gather/CU
// vs VALU 47% / HBM 45% / occ 81% -- nothing saturated); doubling per-wave
// in-flight gathers doubles MLP. VGPR 12 -> ~40, no occupancy impact; col/val
// stay wave-uniform s_load streams. Accumulation order unchanged (bit-identical).
// Round-10's col-chunk sort was a NULL (FETCH byte-identical): within-row ordering
// can't create locality under block churn -- kept (harmless) but not relied on.
// Build pipeline byte-identical to the measured round-9 version.

typedef unsigned short u16;
typedef unsigned int   u32;
typedef unsigned long long u64;

#define USER_ELEMS   (200000 * 64)
#define N_NODES      300000
#define EMB          64
#define NNZ          12800000
#define TOTAL_ELEMS  (N_NODES * EMB)     // 19,200,000

// ---- T0 bucket geometry ----
#define NBUCK    2048
#define ROWS_PB  147                     // 2048*147 = 301,056 >= 300,000
#define EPB      65536                   // edges per block in A passes
#define NB_A     196                     // ceil(NNZ / EPB)
#define CNT_LEN  (NBUCK * NB_A)          // 401,408
#define TILE     4096
#define NTILES   (EPB / TILE)            // 16
#define BCAP     6784                    // bucket LDS capacity (mean 6272, +6.5 sigma)
#define NCH      16                      // col chunks: (col&0x7FFFF)>>15 in [0,15]
#define KEYS     (ROWS_PB * NCH)         // 2352
#define KPT      ((KEYS + 511) / 512)    // 5 bins/thread in bsort scan

// workspace region sizes (bytes)
#define FLAGS_SZ   256ULL
#define ACC_SZ     76800000ULL           // fp32 acc (T2/T3 fallbacks only)
#define EGO_SZ     38400000ULL           // bf16 ego
#define RP_SZ      1200128ULL            // row_ptr (300,032 ints)
#define BS_SZ      1024ULL
#define CNTM_SZ    1605632ULL            // CNT_LEN * 4
#define COL_SZ     51200000ULL           // u32 col per edge (CSR)
#define VALSORT_SZ 25600000ULL           // bf16 val per edge (CSR)
#define BIG_SZ     115200000ULL          // max(stage u64 102.4M, e0+e1+e2 115.2M)
#define PERM_SZ    51200000ULL
#define LAYER_SZ   76800000ULL

#define T0_NEED (FLAGS_SZ + CNTM_SZ + 2*BS_SZ + COL_SZ + VALSORT_SZ + RP_SZ + BIG_SZ) // 194,808,064
#define T2_NEED (FLAGS_SZ + ACC_SZ + EGO_SZ + 2*RP_SZ + 2*BS_SZ + PERM_SZ)            // 168,802,560

__device__ __forceinline__ float bf2f(u16 b) {
    return __uint_as_float(((u32)b) << 16);
}
__device__ __forceinline__ u16 f2bf(float f) {
    u32 u = __float_as_uint(f);
    u32 r = (u + 0x7fffu + ((u >> 16) & 1u)) >> 16;   // round-to-nearest-even
    return (u16)r;
}

// ---------------- dtype detection ----------------
__global__ void k_detect(const u16* __restrict__ emb, const u16* __restrict__ vals,
                         int* __restrict__ flags) {
    int lane = threadIdx.x;                 // 64 threads, 1 wave
    u16 a = emb[lane * 2];
    int ea = (a >> 7) & 0xFF;
    bool pa = (ea >= 0x60 && ea <= 0x7E);
    unsigned long long ba = __ballot(pa);
    u16 b = vals[lane * 2];
    int eb = (b >> 7) & 0xFF;
    bool pb = (eb >= 0x60 && eb <= 0x7E);
    unsigned long long bb = __ballot(pb);
    if (lane == 0) {
        flags[0] = (__popcll(ba) >= 56) ? 0 : 1;   // 0 = bf16, 1 = fp32
        flags[1] = (__popcll(bb) >= 56) ? 0 : 1;
    }
}

// ---------------- init (T0): ego0 bf16 only ----------------
__global__ void k_init_ego(const void* __restrict__ user, const void* __restrict__ item,
                           const int* __restrict__ flags, u16* __restrict__ ego) {
    int t = blockIdx.x * blockDim.x + threadIdx.x;
    int e = t * 4;
    if (e >= TOTAL_ELEMS) return;
    float4 f;
    if (flags[0]) {
        const float* src = (e < USER_ELEMS) ? ((const float*)user + e)
                                            : ((const float*)item + (e - USER_ELEMS));
        f = *(const float4*)src;
    } else {
        const u16* src = (e < USER_ELEMS) ? ((const u16*)user + e)
                                          : ((const u16*)item + (e - USER_ELEMS));
        ushort4 v = *(const ushort4*)src;
        f.x = bf2f(v.x); f.y = bf2f(v.y); f.z = bf2f(v.z); f.w = bf2f(v.w);
    }
    ushort4 o;
    o.x = f2bf(f.x); o.y = f2bf(f.y); o.z = f2bf(f.z); o.w = f2bf(f.w);
    *(ushort4*)(ego + e) = o;
}

// ---------------- init (T2/T3): ego0 bf16 + acc fp32 ----------------
__global__ void k_init(const void* __restrict__ user, const void* __restrict__ item,
                       const int* __restrict__ flags,
                       u16* __restrict__ ego, float* __restrict__ acc) {
    int t = blockIdx.x * blockDim.x + threadIdx.x;
    int e = t * 4;
    if (e >= TOTAL_ELEMS) return;
    float4 f;
    if (flags[0]) {
        const float* src = (e < USER_ELEMS) ? ((const float*)user + e)
                                            : ((const float*)item + (e - USER_ELEMS));
        f = *(const float4*)src;
    } else {
        const u16* src = (e < USER_ELEMS) ? ((const u16*)user + e)
                                          : ((const u16*)item + (e - USER_ELEMS));
        ushort4 v = *(const ushort4*)src;
        f.x = bf2f(v.x); f.y = bf2f(v.y); f.z = bf2f(v.z); f.w = bf2f(v.w);
    }
    ushort4 o;
    o.x = f2bf(f.x); o.y = f2bf(f.y); o.z = f2bf(f.z); o.w = f2bf(f.w);
    *(ushort4*)(ego + e) = o;
    *(float4*)(acc + e) = f;
}

// ---------------- generic 3-phase exclusive scan (EPT = elems/thread) ----------------
template<int EPT>
__global__ void k_scan_reduce(const int* __restrict__ cnt, int* __restrict__ blockSums,
                              int n) {
    __shared__ int s[256];
    int b = blockIdx.x;
    int base = b * (EPT * 256) + threadIdx.x;
    int sum = 0;
#pragma unroll
    for (int k = 0; k < EPT; ++k) {
        int i = base + k * 256;
        if (i < n) sum += cnt[i];
    }
    s[threadIdx.x] = sum;
    __syncthreads();
    for (int off = 128; off > 0; off >>= 1) {
        if (threadIdx.x < (unsigned)off) s[threadIdx.x] += s[threadIdx.x + off];
        __syncthreads();
    }
    if (threadIdx.x == 0) blockSums[b] = s[0];
}

__global__ void k_scan_block(const int* __restrict__ blockSums, int* __restrict__ blockOffs,
                             int nb) {
    __shared__ int s[256];
    int x = (threadIdx.x < nb) ? blockSums[threadIdx.x] : 0;
    s[threadIdx.x] = x;
    __syncthreads();
    for (int off = 1; off < 256; off <<= 1) {
        int t = 0;
        if (threadIdx.x >= (unsigned)off) t = s[threadIdx.x - off];
        __syncthreads();
        s[threadIdx.x] += t;
        __syncthreads();
    }
    if (threadIdx.x < nb) blockOffs[threadIdx.x] = s[threadIdx.x] - x;
}

// In-place safe. cursor2 may be null; may alias cnt.
template<int EPT>
__global__ void k_scan_down(const int* cnt, const int* __restrict__ blockOffs,
                            int* __restrict__ out, int* cursor2,
                            int n, int total, int writeTotal) {
    __shared__ int s[256];
    int b = blockIdx.x;
    int base = b * (EPT * 256) + threadIdx.x * EPT;
    int v[EPT];
    int tsum = 0;
#pragma unroll
    for (int k = 0; k < EPT; ++k) {
        int i = base + k;
        v[k] = (i < n) ? cnt[i] : 0;
        tsum += v[k];
    }
    s[threadIdx.x] = tsum;
    __syncthreads();
    for (int off = 1; off < 256; off <<= 1) {
        int t = 0;
        if (threadIdx.x >= (unsigned)off) t = s[threadIdx.x - off];
        __syncthreads();
        s[threadIdx.x] += t;
        __syncthreads();
    }
    int running = blockOffs[b] + (s[threadIdx.x] - tsum);
#pragma unroll
    for (int k = 0; k < EPT; ++k) {
        int i = base + k;
        if (i < n) {
            out[i] = running;
            if (cursor2) cursor2[i] = running;
        }
        running += v[k];
    }
    if (writeTotal && b == 0 && threadIdx.x == 0) out[n] = total;
}

// ---------------- A1: per-block bucket histogram ----------------
__global__ void __launch_bounds__(512) k_bhist(const int* __restrict__ rows,
                                               int* __restrict__ counts) {
    __shared__ int c[NBUCK];
    for (int i = threadIdx.x; i < NBUCK; i += 512) c[i] = 0;
    __syncthreads();
    int b0 = blockIdx.x * EPB;
    for (int i = threadIdx.x; i < EPB; i += 512) {
        int e = b0 + i;
        if (e < NNZ) {
            u32 k = (u32)rows[e] / ROWS_PB;
            if (k >= NBUCK) k = NBUCK - 1;          // guard: bad row -> clamp
            atomicAdd(&c[k], 1);
        }
    }
    __syncthreads();
    for (int k = threadIdx.x; k < NBUCK; k += 512)
        counts[k * NB_A + blockIdx.x] = c[k];
}

// ---------------- A3: tile-staged multisplit scatter ----------------
__global__ void __launch_bounds__(512) k_bscatter(
    const int* __restrict__ rows, const int* __restrict__ cols,
    const void* __restrict__ vals, const int* __restrict__ flags,
    const int* __restrict__ offs, u64* __restrict__ stg) {
    __shared__ int h[NBUCK];        // 8KB  per-tile bucket counts
    __shared__ u16 o[NBUCK];        // 4KB  inclusive scan of h (<=4096 fits u16)
    __shared__ int gbase[NBUCK];    // 8KB  running global write base per bucket
    __shared__ u64 st[TILE];        // 32KB staged payloads
    __shared__ u16 kst[TILE];       // 8KB  staged bucket ids      (total 60KB)
    int b = blockIdx.x, tid = threadIdx.x;
    for (int i = tid; i < NBUCK; i += 512) gbase[i] = offs[i * NB_A + b];
    int valF32 = flags[1];
    for (int t = 0; t < NTILES; ++t) {
        for (int i = tid; i < NBUCK; i += 512) h[i] = 0;
        __syncthreads();
        int ebase = b * EPB + t * TILE;
        int kk[8]; int rk[8]; u64 pl[8];
#pragma unroll
        for (int j = 0; j < 8; ++j) {
            int e = ebase + tid + j * 512;
            kk[j] = -1;
            if (e < NNZ) {
                u32 r = (u32)rows[e];
                u32 c = (u32)cols[e] & 0x7FFFFu;     // guard: 19-bit col
                u16 v = valF32 ? f2bf(((const float*)vals)[e]) : ((const u16*)vals)[e];
                u32 k = r / ROWS_PB;
                if (k >= NBUCK) k = NBUCK - 1;       // guard: bad row -> clamp
                u32 rl = r - k * ROWS_PB;
                if (rl >= ROWS_PB) rl = ROWS_PB - 1; // guard
                kk[j] = (int)k;
                pl[j] = ((u64)v << 32) | (u64)((rl << 19) | c);
                rk[j] = atomicAdd(&h[k], 1);
            }
        }
        __syncthreads();
        for (int i = tid; i < NBUCK; i += 512) o[i] = (u16)h[i];
        __syncthreads();
        for (int off = 1; off < NBUCK; off <<= 1) {   // Hillis-Steele inclusive
            u16 t0[4];
#pragma unroll
            for (int q = 0; q < 4; ++q) {
                int i = tid + q * 512;
                t0[q] = (i >= off) ? o[i - off] : (u16)0;
            }
            __syncthreads();
#pragma unroll
            for (int q = 0; q < 4; ++q) o[tid + q * 512] += t0[q];
            __syncthreads();
        }
#pragma unroll
        for (int j = 0; j < 8; ++j) {
            if (kk[j] >= 0) {
                int excl = (int)o[kk[j]] - h[kk[j]];
                int p = excl + rk[j];
                if (p >= 0 && p < TILE) {            // guard: never OOB LDS
                    st[p] = pl[j];
                    kst[p] = (u16)kk[j];
                }
            }
        }
        __syncthreads();
        int cnt = (int)o[NBUCK - 1];
        if (cnt > TILE) cnt = TILE;                  // guard
        for (int i = tid; i < cnt; i += 512) {
            int k = kst[i];
            int excl = (int)o[k] - h[k];
            long long p = (long long)gbase[k] + (i - excl);
            if (p >= 0 && p < NNZ) stg[p] = st[i];   // guard: never OOB global
        }
        __syncthreads();
        for (int i = tid; i < NBUCK; i += 512) gbase[i] += h[i];
        __syncthreads();
    }
}

// ---------------- B: per-bucket (row, col-chunk) sort -> CSR + row_ptr ----------------
__global__ void __launch_bounds__(512) k_bsort(
    const int* __restrict__ offs, const u64* __restrict__ stg,
    int* __restrict__ col_s, u16* __restrict__ val_s, int* __restrict__ row_ptr) {
    __shared__ int h[KEYS];             // 9,408B  bin counts
    __shared__ int ex[KEYS];            // 9,408B  exclusive offsets -> cursors
    __shared__ int s512[512];           // 2,048B  block scan
    __shared__ u32 lcol[BCAP];          // 27,136B
    __shared__ u16 lval[BCAP];          // 13,568B  (total 61.5KB -> 2 wg/CU)
    int k = blockIdx.x, tid = threadIdx.x;
    int s = offs[k * NB_A];
    int e = (k == NBUCK - 1) ? NNZ : offs[(k + 1) * NB_A];
    if (e > NNZ) e = NNZ;                            // guard
    if (s < 0) s = 0;                                // guard
    for (int i = tid; i < KEYS; i += 512) h[i] = 0;
    __syncthreads();
    for (int j = s + tid; j < e; j += 512) {
        u32 lo = (u32)stg[j];
        u32 rl = lo >> 19;
        if (rl >= ROWS_PB) rl = ROWS_PB - 1;         // guard (stale staging)
        u32 ch = (lo & 0x7FFFFu) >> 15;              // 0..15 by construction
        atomicAdd(&h[rl * NCH + ch], 1);
    }
    __syncthreads();
    // block-parallel exclusive scan over KEYS bins (KPT bins/thread)
    int loc[KPT]; int tsum = 0; int base = tid * KPT;
#pragma unroll
    for (int q = 0; q < KPT; ++q) {
        int i = base + q;
        loc[q] = (i < KEYS) ? h[i] : 0;
        tsum += loc[q];
    }
    s512[tid] = tsum;
    __syncthreads();
    for (int off = 1; off < 512; off <<= 1) {
        int t = 0;
        if (tid >= off) t = s512[tid - off];
        __syncthreads();
        s512[tid] += t;
        __syncthreads();
    }
    int run = s512[tid] - tsum;
#pragma unroll
    for (int q = 0; q < KPT; ++q) {
        int i = base + q;
        if (i < KEYS) { ex[i] = run; run += loc[q]; }
    }
    __syncthreads();
    // row_ptr from chunk-0 bins (before ex is consumed as cursors)
    int rowbase = k * ROWS_PB;
    for (int i = tid; i < ROWS_PB; i += 512) {
        int r = rowbase + i;
        if (r <= N_NODES) row_ptr[r] = s + ex[i * NCH];
    }
    __syncthreads();
    int n = e - s;
    for (int j = s + tid; j < e; j += 512) {
        u64 pk = stg[j];
        u32 lo = (u32)pk;
        u32 rl = lo >> 19;
        if (rl >= ROWS_PB) rl = ROWS_PB - 1;         // guard
        u32 ch = (lo & 0x7FFFFu) >> 15;
        int p = atomicAdd(&ex[rl * NCH + ch], 1);
        if (p >= 0 && p < BCAP) { lcol[p] = lo & 0x7FFFFu; lval[p] = (u16)(pk >> 32); }
        else if (p >= 0 && p < n) {                  // overflow fallback, guarded
            col_s[s + p] = (int)(lo & 0x7FFFFu); val_s[s + p] = (u16)(pk >> 32);
        }
    }
    __syncthreads();
    int m = n < BCAP ? n : BCAP;
    for (int i = tid; i < m; i += 512) {
        col_s[s + i] = (int)lcol[i];
        val_s[s + i] = lval[i];
    }
}

// ---------------- SpMM: wave per row, lane = emb dim; 16-deep gather MLP ------
// FINAL=0: writes ego_out bf16. FINAL=1 (layer 3): fuses the output reduction
// out = (e0 + e1 + e2 + a3) / 4 and writes d_out (fp32 or bf16) directly.
template<int FINAL>
__global__ void __launch_bounds__(256) k_spmm(
    const int* __restrict__ row_ptr, const int* __restrict__ col_s,
    const u16* __restrict__ val_s, const u16* __restrict__ ego_in,
    u16* __restrict__ ego_out,
    const u16* __restrict__ e0, const u16* __restrict__ e1,
    const int* __restrict__ flags, void* __restrict__ out) {
    int row = __builtin_amdgcn_readfirstlane(
        (int)((blockIdx.x * blockDim.x + threadIdx.x) >> 6));
    int lane = threadIdx.x & 63;
    if (row >= N_NODES) return;
    int start = row_ptr[row];
    int end   = row_ptr[row + 1];
    float a = 0.f;
    int j = start;
    for (; j + 16 <= end; j += 16) {
        int c[16]; u16 w[16];
#pragma unroll
        for (int q = 0; q < 16; ++q) { c[q] = col_s[j + q]; w[q] = val_s[j + q]; }
        float x[16];
#pragma unroll
        for (int q = 0; q < 16; ++q) {
            u32 cc = (u32)c[q] & 0x7FFFFu;           // bounded gather
            x[q] = bf2f(ego_in[cc * EMB + lane]);
        }
#pragma unroll
        for (int q = 0; q < 16; ++q) a += bf2f(w[q]) * x[q];
    }
    for (; j + 4 <= end; j += 4) {
        int c[4]; u16 w[4];
#pragma unroll
        for (int q = 0; q < 4; ++q) { c[q] = col_s[j + q]; w[q] = val_s[j + q]; }
        float x[4];
#pragma unroll
        for (int q = 0; q < 4; ++q) {
            u32 cc = (u32)c[q] & 0x7FFFFu;
            x[q] = bf2f(ego_in[cc * EMB + lane]);
        }
#pragma unroll
        for (int q = 0; q < 4; ++q) a += bf2f(w[q]) * x[q];
    }
    for (; j < end; ++j) {
        u32 cc = (u32)col_s[j] & 0x7FFFFu;
        a += bf2f(val_s[j]) * bf2f(ego_in[cc * EMB + lane]);
    }
    int o = row * EMB + lane;
    if (FINAL) {
        float s = bf2f(e0[o]) + bf2f(e1[o]) + bf2f(ego_in[o]) + a;  // ego_in == e2
        s *= 0.25f;
        if (flags[0]) ((float*)out)[o] = s;
        else          ((u16*)out)[o]  = f2bf(s);
    } else {
        ego_out[o] = f2bf(a);
    }
}

// ---------------- T2 fallback: CSR by permutation ----------------
__global__ void k_hist(const int* __restrict__ rows, int* __restrict__ cnt) {
    int e = blockIdx.x * blockDim.x + threadIdx.x;
    if (e < NNZ) atomicAdd(&cnt[rows[e]], 1);
}

__global__ void k_scatter_perm(const int* __restrict__ rows, int* __restrict__ cursor,
                               u32* __restrict__ perm) {
    int e = blockIdx.x * blockDim.x + threadIdx.x;
    if (e >= NNZ) return;
    int r = rows[e];
    int p = atomicAdd(&cursor[r], 1);
    perm[p] = (u32)e;
}

__global__ void __launch_bounds__(256) k_spmm_perm(
    const int* __restrict__ row_ptr, const u32* __restrict__ perm,
    const int* __restrict__ cols, const void* __restrict__ vals,
    const int* __restrict__ flags, const u16* __restrict__ ego_in,
    u16* __restrict__ ego_out, float* __restrict__ acc) {
    int row = __builtin_amdgcn_readfirstlane(
        (int)((blockIdx.x * blockDim.x + threadIdx.x) >> 6));
    int lane = threadIdx.x & 63;
    if (row >= N_NODES) return;
    int valF32 = flags[1];
    int start = row_ptr[row];
    int end   = row_ptr[row + 1];
    float a = 0.f;
    for (int j = start; j < end; ++j) {
        u32 eid = perm[j];
        int c = cols[eid];
        float w = valF32 ? ((const float*)vals)[eid] : bf2f(((const u16*)vals)[eid]);
        a += w * bf2f(ego_in[c * EMB + lane]);
    }
    int o = row * EMB + lane;
    acc[o] += a;
    ego_out[o] = f2bf(a);
}

// ---------------- T3 fallback: edge-parallel atomics ----------------
__global__ void __launch_bounds__(256) k_edge_atomic(
    const int* __restrict__ rows, const int* __restrict__ cols,
    const void* __restrict__ vals, const int* __restrict__ flags,
    const u16* __restrict__ ego, float* __restrict__ layer) {
    int t = blockIdx.x * blockDim.x + threadIdx.x;
    int e = t >> 4;
    if (e >= NNZ) return;
    int d4 = (t & 15) * 4;
    int r = rows[e], c = cols[e];
    float w = flags[1] ? ((const float*)vals)[e] : bf2f(((const u16*)vals)[e]);
    ushort4 x = *(const ushort4*)(ego + c * EMB + d4);
    float* dst = layer + r * EMB + d4;
    atomicAdd(dst + 0, w * bf2f(x.x));
    atomicAdd(dst + 1, w * bf2f(x.y));
    atomicAdd(dst + 2, w * bf2f(x.z));
    atomicAdd(dst + 3, w * bf2f(x.w));
}

__global__ void k_layer_fin(float* __restrict__ layer, float* __restrict__ acc,
                            u16* __restrict__ ego) {
    int t = blockIdx.x * blockDim.x + threadIdx.x;
    int e = t * 4;
    if (e >= TOTAL_ELEMS) return;
    float4 L = *(const float4*)(layer + e);
    float4 A = *(const float4*)(acc + e);
    A.x += L.x; A.y += L.y; A.z += L.z; A.w += L.w;
    *(float4*)(acc + e) = A;
    ushort4 o;
    o.x = f2bf(L.x); o.y = f2bf(L.y); o.z = f2bf(L.z); o.w = f2bf(L.w);
    *(ushort4*)(ego + e) = o;
    float4 z; z.x = 0.f; z.y = 0.f; z.z = 0.f; z.w = 0.f;
    *(float4*)(layer + e) = z;
}

// ---------------- finalize (T2/T3): out = (acc / 4) ----------------
__global__ void k_final(const float* __restrict__ acc, const int* __restrict__ flags,
                        void* __restrict__ out) {
    int t = blockIdx.x * blockDim.x + threadIdx.x;
    int e = t * 4;
    if (e >= TOTAL_ELEMS) return;
    float4 f = *(const float4*)(acc + e);
    f.x *= 0.25f; f.y *= 0.25f; f.z *= 0.25f; f.w *= 0.25f;
    if (flags[0]) {
        *(float4*)((float*)out + e) = f;
    } else {
        ushort4 v;
        v.x = f2bf(f.x); v.y = f2bf(f.y); v.z = f2bf(f.z); v.w = f2bf(f.w);
        *(ushort4*)((u16*)out + e) = v;
    }
}

extern "C" void kernel_launch(void* const* d_in, const int* in_sizes, int n_in,
                              void* d_out, int out_size, void* d_ws, size_t ws_size,
                              hipStream_t stream) {
    const void* user = d_in[0];
    const void* item = d_in[1];
    const void* vals = d_in[2];
    const int*  rows = (const int*)d_in[3];
    const int*  cols = (const int*)d_in[4];

    char* ws = (char*)d_ws;
    int* flags = (int*)ws;

    const int initGrid = (TOTAL_ELEMS / 4 + 255) / 256;   // 18750
    const int edgeGrid = (NNZ + 255) / 256;                // 50000
    const int spmmGrid = (N_NODES * 64) / 256;             // 75000

    k_detect<<<1, 64, 0, stream>>>((const u16*)user, (const u16*)vals, flags);

    if (ws_size >= T0_NEED) {
        // ---- T0: bucket build -> CSR (col-chunk ordered) -> 3x spmm ----
        size_t off = FLAGS_SZ;
        int* cntm = (int*)(ws + off); off += CNTM_SZ;     // counts -> offsets (in place)
        int* bs2  = (int*)(ws + off); off += BS_SZ;
        int* bo2  = (int*)(ws + off); off += BS_SZ;
        int* col_s = (int*)(ws + off); off += COL_SZ;     // plain col (CSR order)
        u16* val_s = (u16*)(ws + off); off += VALSORT_SZ;
        int* row_ptr = (int*)(ws + off); off += RP_SZ;
        char* big  = ws + off;                            // 115.2MB shared region
        u64* stg = (u64*)big;                             // staging (dead after k_bsort)
        u16* e0  = (u16*)big;                             // live after k_init_ego
        u16* e1  = (u16*)(big + EGO_SZ);
        u16* e2  = (u16*)(big + 2 * EGO_SZ);

        k_bhist<<<NB_A, 512, 0, stream>>>(rows, cntm);
        // k-major exclusive scan of the 2048 x 196 count matrix (in place)
        k_scan_reduce<16><<<98, 256, 0, stream>>>(cntm, bs2, CNT_LEN);
        k_scan_block<<<1, 256, 0, stream>>>(bs2, bo2, 98);
        k_scan_down<16><<<98, 256, 0, stream>>>(cntm, bo2, cntm, (int*)0, CNT_LEN, 0, 0);

        k_bscatter<<<NB_A, 512, 0, stream>>>(rows, cols, vals, flags, cntm, stg);
        k_bsort<<<NBUCK, 512, 0, stream>>>(cntm, stg, col_s, val_s, row_ptr);

        k_init_ego<<<initGrid, 256, 0, stream>>>(user, item, flags, e0); // after bsort: e0 aliases stg
        // dummy (valid) pointers for unused template-dead args
        k_spmm<0><<<spmmGrid, 256, 0, stream>>>(row_ptr, col_s, val_s, e0, e1,
                                                e0, e1, flags, (void*)d_out);
        k_spmm<0><<<spmmGrid, 256, 0, stream>>>(row_ptr, col_s, val_s, e1, e2,
                                                e0, e1, flags, (void*)d_out);
        k_spmm<1><<<spmmGrid, 256, 0, stream>>>(row_ptr, col_s, val_s, e2, e1,
                                                e0, e1, flags, d_out);
    } else if (ws_size >= T2_NEED) {
        // ---- T2: permutation CSR ----
        size_t off = FLAGS_SZ;
        float* acc = (float*)(ws + off); off += ACC_SZ;
        u16* ego0 = (u16*)d_out;
        u16* ego1 = (u16*)(ws + off); off += EGO_SZ;
        int* row_ptr = (int*)(ws + off); off += RP_SZ;
        int* cursor  = (int*)(ws + off); off += RP_SZ;
        int* bsums   = (int*)(ws + off); off += BS_SZ;
        int* boffs   = (int*)(ws + off); off += BS_SZ;
        u32* perm    = (u32*)(ws + off); off += PERM_SZ;

        hipMemsetAsync(cursor, 0, N_NODES * sizeof(int), stream);
        k_init<<<initGrid, 256, 0, stream>>>(user, item, flags, ego0, acc);
        k_hist<<<edgeGrid, 256, 0, stream>>>(rows, cursor);
        k_scan_reduce<8><<<147, 256, 0, stream>>>(cursor, bsums, N_NODES);
        k_scan_block<<<1, 256, 0, stream>>>(bsums, boffs, 147);
        k_scan_down<8><<<147, 256, 0, stream>>>(cursor, boffs, row_ptr, cursor,
                                                N_NODES, NNZ, 1);
        k_scatter_perm<<<edgeGrid, 256, 0, stream>>>(rows, cursor, perm);
        k_spmm_perm<<<spmmGrid, 256, 0, stream>>>(row_ptr, perm, cols, vals, flags,
                                                  ego0, ego1, acc);
        k_spmm_perm<<<spmmGrid, 256, 0, stream>>>(row_ptr, perm, cols, vals, flags,
                                                  ego1, ego0, acc);
        k_spmm_perm<<<spmmGrid, 256, 0, stream>>>(row_ptr, perm, cols, vals, flags,
                                                  ego0, ego1, acc);
        k_final<<<initGrid, 256, 0, stream>>>(acc, flags, d_out);
    } else {
        // ---- T3: edge-parallel atomics, minimal footprint ----
        size_t off = FLAGS_SZ;
        float* acc   = (float*)(ws + off); off += ACC_SZ;
        float* layer = (float*)(ws + off); off += LAYER_SZ;
        u16* ego = (u16*)d_out;
        hipMemsetAsync(layer, 0, LAYER_SZ, stream);
        k_init<<<initGrid, 256, 0, stream>>>(user, item, flags, ego, acc);
        const int atomGrid = (NNZ * 16) / 256;
        for (int l = 0; l < 3; ++l) {
            k_edge_atomic<<<atomGrid, 256, 0, stream>>>(rows, cols, vals, flags, ego, layer);
            k_layer_fin<<<initGrid, 256, 0, stream>>>(layer, acc, ego);
        }
        k_final<<<initGrid, 256, 0, stream>>>(acc, flags, d_out);
    }
}